// Round 9
// baseline (109.425 us; speedup 1.0000x reference)
//
#include <hip/hip_runtime.h>

// ============================================================================
// MEASUREMENT ROUND: gat_main is the R4 (best, 56us) kernel with the j-loop
// run 3x (jc<96, chunk indices wrap via &31). Output is numerically identical
// (acc and Sden both scale 3x; ratio invariant). Purpose: force gat_main above
// the harness's 76us poison-fill dispatches so its PMC counters appear in the
// top-5 view, attributing the 56us: VALUBusy? hbm? LDS conflicts? VGPR/spill?
// ============================================================================

#define NB 8
#define NN 2048
#define FIN 256
#define FOUT 128

typedef __attribute__((ext_vector_type(8))) short short8;
typedef __attribute__((ext_vector_type(4))) float f32x4;

static __device__ __forceinline__ unsigned short f2bf(float f) {
    unsigned int u = __float_as_uint(f);
    u += 0x7fffu + ((u >> 16) & 1u);
    return (unsigned short)(u >> 16);
}

// Raw barrier: LDS writes visible (lgkmcnt(0)); global loads stay in flight.
#define BAR_LGKM()                                            \
    do {                                                      \
        asm volatile("s_waitcnt lgkmcnt(0)" ::: "memory");    \
        __builtin_amdgcn_sched_barrier(0);                    \
        __builtin_amdgcn_s_barrier();                         \
        __builtin_amdgcn_sched_barrier(0);                    \
    } while (0)

// K1: unchanged (verified since R1).
__global__ __launch_bounds__(256) void gat_prep(
    const float* __restrict__ h, const float* __restrict__ W, const float* __restrict__ a,
    unsigned short* __restrict__ whpv, float* __restrict__ s1g, float* __restrict__ s2g)
{
    __shared__ __align__(16) float hT[64 * FIN];
    __shared__ __align__(16) unsigned short pvs[8192];
    const int t = threadIdx.x;
    const int bx = blockIdx.x;
    const int b = bx >> 5;
    const int jt = bx & 31;
    const int j0 = jt * 64;

    const float* hsrc = h + ((size_t)b * NN + j0) * FIN;
    #pragma unroll
    for (int p = 0; p < 16; ++p) {
        int idx = p * 256 + t;
        *(f32x4*)&hT[idx * 4] = *(const f32x4*)&hsrc[idx * 4];
    }
    __syncthreads();

    const int cg = t & 31;
    const int rg = t >> 5;
    float acc[8][4];
    #pragma unroll
    for (int r = 0; r < 8; ++r)
        #pragma unroll
        for (int q = 0; q < 4; ++q) acc[r][q] = 0.f;

    for (int f = 0; f < FIN; f += 4) {
        f32x4 wv[4];
        #pragma unroll
        for (int q = 0; q < 4; ++q) wv[q] = *(const f32x4*)&W[(f + q) * FOUT + cg * 4];
        #pragma unroll
        for (int r = 0; r < 8; ++r) {
            f32x4 hv = *(const f32x4*)&hT[(rg * 8 + r) * FIN + f];
            #pragma unroll
            for (int q = 0; q < 4; ++q) {
                acc[r][0] += hv[q] * wv[q][0];
                acc[r][1] += hv[q] * wv[q][1];
                acc[r][2] += hv[q] * wv[q][2];
                acc[r][3] += hv[q] * wv[q][3];
            }
        }
    }

    f32x4 a1v = *(const f32x4*)&a[cg * 4];
    f32x4 a2v = *(const f32x4*)&a[FOUT + cg * 4];
    #pragma unroll
    for (int r = 0; r < 8; ++r) {
        float p1 = acc[r][0]*a1v[0] + acc[r][1]*a1v[1] + acc[r][2]*a1v[2] + acc[r][3]*a1v[3];
        float p2 = acc[r][0]*a2v[0] + acc[r][1]*a2v[1] + acc[r][2]*a2v[2] + acc[r][3]*a2v[3];
        #pragma unroll
        for (int m = 16; m >= 1; m >>= 1) {
            p1 += __shfl_xor(p1, m, 64);
            p2 += __shfl_xor(p2, m, 64);
        }
        if (cg == 0) {
            s1g[b * NN + j0 + rg * 8 + r] = p1;
            s2g[b * NN + j0 + rg * 8 + r] = p2;
        }
    }

    #pragma unroll
    for (int r = 0; r < 8; ++r) {
        int jl = rg * 8 + r;
        int kt = jl >> 5, j5 = jl & 31, g = j5 >> 3, i = j5 & 7;
        #pragma unroll
        for (int q = 0; q < 4; ++q) {
            int c = cg * 4 + q;
            int lane = g * 16 + (c & 15);
            int nt = c >> 4;
            pvs[((kt * 8 + nt) * 64 + lane) * 8 + i] = f2bf(acc[r][q]);
        }
    }
    __syncthreads();
    unsigned short* dst = whpv + (size_t)(b * 32 + jt) * 8192;
    #pragma unroll
    for (int p = 0; p < 4; ++p) {
        int idx = p * 2048 + t * 8;
        *(short8*)&dst[idx] = *(const short8*)&pvs[idx];
    }
}

// K2: R4 kernel verbatim, except the loop runs 96 iterations (3 passes over the
// 32 j-chunks). acc and ssum triple; acc/Sden is unchanged.
__global__ __launch_bounds__(512, 4) void gat_main(
    const int* __restrict__ adj, const unsigned short* __restrict__ whpv,
    const float* __restrict__ s1g, const float* __restrict__ s2g, float* __restrict__ out)
{
    __shared__ __align__(16) char Plds[2][32 * 128];       // 2 x 4 KB: [row][slot^ (16B)]
    __shared__ __align__(16) unsigned short BL[2][8192];   // 2 x 16 KB: B fragments
    __shared__ float Sden[32];

    const int t = threadIdx.x;
    const int bx = blockIdx.x;
    const int b = bx & 7;            // XCD affinity: whpv[b] L2-resident
    const int i0 = (bx >> 3) * 32;

    const int r  = t >> 4;
    const int jq = t & 15;

    const int lane = t & 63;
    const int w = t >> 6;
    const int mt = w & 1;
    const int nb = w >> 1;
    const int arow = mt * 16 + (lane & 15);
    const int g = lane >> 4;

    const float s1v = s1g[b * NN + i0 + r];

    f32x4 acc[2];
    acc[0] = (f32x4){0.f, 0.f, 0.f, 0.f};
    acc[1] = (f32x4){0.f, 0.f, 0.f, 0.f};
    float ssum = 0.f;

    const int* adjb = adj + (size_t)b * NN * NN + (size_t)i0 * NN;
    const int* aptr = adjb + (size_t)r * NN + jq * 4;
    const unsigned short* whb = whpv + (size_t)b * 32 * 8192;
    const float* s2b = s2g + b * NN;

    // depth-2 prefetch registers
    int4   ac[2];
    short8 wf0[2], wf1[2];
    f32x4  s2r[2];
    ac[0]  = *(const int4*)aptr;
    wf0[0] = *(const short8*)&whb[t * 8];
    wf1[0] = *(const short8*)&whb[4096 + t * 8];
    s2r[0] = *(const f32x4*)&s2b[jq * 4];
    ac[1]  = *(const int4*)(aptr + 64);
    wf0[1] = *(const short8*)&whb[8192 + t * 8];
    wf1[1] = *(const short8*)&whb[8192 + 4096 + t * 8];
    s2r[1] = *(const f32x4*)&s2b[64 + jq * 4];

    const int pbyte = r * 128 + ((jq >> 1) ^ (r & 7)) * 16 + (jq & 1) * 8;
    const int abyte = arow * 128;

    #pragma unroll 2   // keeps slot/buf literal
    for (int jc = 0; jc < 96; ++jc) {   // MEASUREMENT: 3 passes (was 32)
        const int slot = jc & 1;
        const int buf  = jc & 1;

        int4   a_  = ac[slot];
        short8 wc0 = wf0[slot];
        short8 wc1 = wf1[slot];
        f32x4  s2v = s2r[slot];

        const int jn = (jc + 2) & 31;   // wraps every pass
        ac[slot]  = *(const int4*)(aptr + jn * 64);
        wf0[slot] = *(const short8*)&whb[(size_t)jn * 8192 + t * 8];
        wf1[slot] = *(const short8*)&whb[(size_t)jn * 8192 + 4096 + t * 8];
        s2r[slot] = *(const f32x4*)&s2b[jn * 64 + jq * 4];

        float p0, p1, p2, p3;
        {
            float e0 = s1v + s2v[0]; e0 = fmaxf(e0, 0.2f * e0);
            p0 = (a_.x > 0) ? __expf(e0) : 0.f;
            float e1 = s1v + s2v[1]; e1 = fmaxf(e1, 0.2f * e1);
            p1 = (a_.y > 0) ? __expf(e1) : 0.f;
            float e2 = s1v + s2v[2]; e2 = fmaxf(e2, 0.2f * e2);
            p2 = (a_.z > 0) ? __expf(e2) : 0.f;
            float e3 = s1v + s2v[3]; e3 = fmaxf(e3, 0.2f * e3);
            p3 = (a_.w > 0) ? __expf(e3) : 0.f;
        }
        ssum += (p0 + p1) + (p2 + p3);
        unsigned int pk0 = (unsigned int)f2bf(p0) | ((unsigned int)f2bf(p1) << 16);
        unsigned int pk1 = (unsigned int)f2bf(p2) | ((unsigned int)f2bf(p3) << 16);
        uint2 pk = {pk0, pk1};
        *(uint2*)&Plds[buf][pbyte] = pk;

        *(short8*)&BL[buf][t * 8] = wc0;
        *(short8*)&BL[buf][4096 + t * 8] = wc1;

        BAR_LGKM();

        #pragma unroll
        for (int kt = 0; kt < 2; ++kt) {
            int aslot = (4 * kt + g) ^ (arow & 7);
            short8 af = *(const short8*)&Plds[buf][abyte + aslot * 16];
            #pragma unroll
            for (int n = 0; n < 2; ++n) {
                int nt = nb * 2 + n;
                short8 bfr = *(const short8*)&BL[buf][((kt * 8 + nt) * 64 + lane) * 8];
                acc[n] = __builtin_amdgcn_mfma_f32_16x16x32_bf16(af, bfr, acc[n], 0, 0, 0);
            }
        }
    }

    {
        float v = ssum;
        #pragma unroll
        for (int m = 8; m >= 1; m >>= 1) v += __shfl_xor(v, m, 64);
        if (jq == 0) Sden[r] = v;
    }
    __syncthreads();

    float* ob = out + ((size_t)b * NN + i0) * FOUT;
    #pragma unroll
    for (int n = 0; n < 2; ++n) {
        int col = (nb * 2 + n) * 16 + (lane & 15);
        #pragma unroll
        for (int q = 0; q < 4; ++q) {
            int row = mt * 16 + (lane >> 4) * 4 + q;
            ob[(size_t)row * FOUT + col] = acc[n][q] / Sden[row];
        }
    }
}

extern "C" void kernel_launch(void* const* d_in, const int* in_sizes, int n_in,
                              void* d_out, int out_size, void* d_ws, size_t ws_size,
                              hipStream_t stream) {
    (void)in_sizes; (void)n_in; (void)out_size; (void)ws_size;
    const float* h   = (const float*)d_in[0];
    const int*   adj = (const int*)d_in[1];
    const float* W   = (const float*)d_in[2];
    const float* a   = (const float*)d_in[3];
    float* out = (float*)d_out;

    unsigned short* whpv = (unsigned short*)d_ws;                               // 4 MB
    float* s1g = (float*)((char*)d_ws + (4u << 20));                            // 64 KB
    float* s2g = (float*)((char*)d_ws + (4u << 20) + (64u << 10));              // 64 KB

    gat_prep<<<dim3(256), dim3(256), 0, stream>>>(h, W, a, whpv, s1g, s2g);
    gat_main<<<dim3(512), dim3(512), 0, stream>>>(adj, whpv, s1g, s2g, out);
}

// Round 10
// 99.111 us; speedup vs baseline: 1.1041x; 1.1041x over previous
//
#include <hip/hip_runtime.h>

#define NB 8
#define NN 2048
#define FIN 256
#define FOUT 128

typedef __attribute__((ext_vector_type(8))) short short8;
typedef __attribute__((ext_vector_type(4))) float f32x4;
typedef __attribute__((ext_vector_type(4))) int i32x4;
typedef __attribute__((ext_vector_type(4))) unsigned int u32x4;

static __device__ __forceinline__ unsigned short f2bf(float f) {
    unsigned int u = __float_as_uint(f);
    u += 0x7fffu + ((u >> 16) & 1u);
    return (unsigned short)(u >> 16);
}

// Raw barrier: LDS writes visible (lgkmcnt(0)); global loads stay in flight.
#define BAR_LGKM()                                            \
    do {                                                      \
        asm volatile("s_waitcnt lgkmcnt(0)" ::: "memory");    \
        __builtin_amdgcn_sched_barrier(0);                    \
        __builtin_amdgcn_s_barrier();                         \
        __builtin_amdgcn_sched_barrier(0);                    \
    } while (0)

// K1: unchanged (verified since R1). Wh = h@W fp32; emits s1/s2 + WhPV bf16 fragments.
// WhPV layout per 64-j chunk: [kt(2)][nt(8)][lane(64)][i(8)],
//   element = Wh[j0 + 32*kt + 8*(lane>>4) + i][16*nt + (lane&15)]   (sigma(g,i)=8g+i)
__global__ __launch_bounds__(256) void gat_prep(
    const float* __restrict__ h, const float* __restrict__ W, const float* __restrict__ a,
    unsigned short* __restrict__ whpv, float* __restrict__ s1g, float* __restrict__ s2g)
{
    __shared__ __align__(16) float hT[64 * FIN];
    __shared__ __align__(16) unsigned short pvs[8192];
    const int t = threadIdx.x;
    const int bx = blockIdx.x;
    const int b = bx >> 5;
    const int jt = bx & 31;
    const int j0 = jt * 64;

    const float* hsrc = h + ((size_t)b * NN + j0) * FIN;
    #pragma unroll
    for (int p = 0; p < 16; ++p) {
        int idx = p * 256 + t;
        *(f32x4*)&hT[idx * 4] = *(const f32x4*)&hsrc[idx * 4];
    }
    __syncthreads();

    const int cg = t & 31;
    const int rg = t >> 5;
    float acc[8][4];
    #pragma unroll
    for (int r = 0; r < 8; ++r)
        #pragma unroll
        for (int q = 0; q < 4; ++q) acc[r][q] = 0.f;

    for (int f = 0; f < FIN; f += 4) {
        f32x4 wv[4];
        #pragma unroll
        for (int q = 0; q < 4; ++q) wv[q] = *(const f32x4*)&W[(f + q) * FOUT + cg * 4];
        #pragma unroll
        for (int r = 0; r < 8; ++r) {
            f32x4 hv = *(const f32x4*)&hT[(rg * 8 + r) * FIN + f];
            #pragma unroll
            for (int q = 0; q < 4; ++q) {
                acc[r][0] += hv[q] * wv[q][0];
                acc[r][1] += hv[q] * wv[q][1];
                acc[r][2] += hv[q] * wv[q][2];
                acc[r][3] += hv[q] * wv[q][3];
            }
        }
    }

    f32x4 a1v = *(const f32x4*)&a[cg * 4];
    f32x4 a2v = *(const f32x4*)&a[FOUT + cg * 4];
    #pragma unroll
    for (int r = 0; r < 8; ++r) {
        float p1 = acc[r][0]*a1v[0] + acc[r][1]*a1v[1] + acc[r][2]*a1v[2] + acc[r][3]*a1v[3];
        float p2 = acc[r][0]*a2v[0] + acc[r][1]*a2v[1] + acc[r][2]*a2v[2] + acc[r][3]*a2v[3];
        #pragma unroll
        for (int m = 16; m >= 1; m >>= 1) {
            p1 += __shfl_xor(p1, m, 64);
            p2 += __shfl_xor(p2, m, 64);
        }
        if (cg == 0) {
            s1g[b * NN + j0 + rg * 8 + r] = p1;
            s2g[b * NN + j0 + rg * 8 + r] = p2;
        }
    }

    #pragma unroll
    for (int r = 0; r < 8; ++r) {
        int jl = rg * 8 + r;
        int kt = jl >> 5, j5 = jl & 31, g = j5 >> 3, i = j5 & 7;
        #pragma unroll
        for (int q = 0; q < 4; ++q) {
            int c = cg * 4 + q;
            int lane = g * 16 + (c & 15);
            int nt = c >> 4;
            pvs[((kt * 8 + nt) * 64 + lane) * 8 + i] = f2bf(acc[r][q]);
        }
    }
    __syncthreads();
    unsigned short* dst = whpv + (size_t)(b * 32 + jt) * 8192;
    #pragma unroll
    for (int p = 0; p < 4; ++p) {
        int idx = p * 2048 + t * 8;
        *(short8*)&dst[idx] = *(const short8*)&pvs[idx];
    }
}

static __device__ __forceinline__ uint2 pquad(i32x4 av, f32x4 s2v, float s1v, float& ssum) {
    float e0 = s1v + s2v[0]; e0 = fmaxf(e0, 0.2f * e0);
    float p0 = (av.x > 0) ? __expf(e0) : 0.f;
    float e1 = s1v + s2v[1]; e1 = fmaxf(e1, 0.2f * e1);
    float p1 = (av.y > 0) ? __expf(e1) : 0.f;
    float e2 = s1v + s2v[2]; e2 = fmaxf(e2, 0.2f * e2);
    float p2 = (av.z > 0) ? __expf(e2) : 0.f;
    float e3 = s1v + s2v[3]; e3 = fmaxf(e3, 0.2f * e3);
    float p3 = (av.w > 0) ? __expf(e3) : 0.f;
    ssum += (p0 + p1) + (p2 + p3);
    uint2 pk;
    pk.x = (unsigned int)f2bf(p0) | ((unsigned int)f2bf(p1) << 16);
    pk.y = (unsigned int)f2bf(p2) | ((unsigned int)f2bf(p3) << 16);
    return pk;
}

// K2 v9 (split-K): block = (batch b, 128-row i-tile, 512-j quarter). whpv L2 traffic
// drops 4x (128 KB/block). Emits UNNORMALIZED partial output + row-sum partials.
// 8 chunks of 64 j; P via swizzled LDS dbuf; B staged to LDS dbuf; depth-1 prefetch;
// lgkm-only barrier (1 per chunk).
__global__ __launch_bounds__(512, 4) void gat_main(
    const int* __restrict__ adj, const unsigned short* __restrict__ whpv,
    const float* __restrict__ s1g, const float* __restrict__ s2g,
    float* __restrict__ part, float* __restrict__ spart)
{
    __shared__ __align__(16) char Plds[2][128 * 128];      // 2 x 16 KB (row: 8 16B slots, slot^=(r&7))
    __shared__ __align__(16) unsigned short Bl[2][8192];   // 2 x 16 KB
    __shared__ __align__(16) float s2s[512];

    const int t = threadIdx.x;
    const int bx = blockIdx.x;
    const int b    = bx & 7;          // XCD affinity for whpv[b]
    const int rest = bx >> 3;
    const int it   = rest & 15;       // i-tile (128 rows)
    const int js   = rest >> 4;       // j-quarter (512 j)
    const int i0 = it * 128;

    // P mapping: row r (0..127), j-16-group q4 (0..3)
    const int r  = t >> 2;
    const int q4 = t & 3;

    // MFMA mapping: wave w = mt (0..7); all 8 nt
    const int lane = t & 63;
    const int w = t >> 6;
    const int g = lane >> 4;
    const int c15 = lane & 15;

    // stage s2 for this j-quarter
    s2s[t] = s2g[b * NN + js * 512 + t];

    const float s1v = s1g[b * NN + i0 + r];
    const int* aptr = adj + (size_t)b * NN * NN + (size_t)(i0 + r) * NN + js * 512 + q4 * 16;
    const unsigned short* whb = whpv + (size_t)b * 32 * 8192 + (size_t)js * 8 * 8192;

    f32x4 acc[8];
    #pragma unroll
    for (int nt = 0; nt < 8; ++nt) acc[nt] = (f32x4){0.f, 0.f, 0.f, 0.f};
    float ssum = 0.f;

    // prologue: chunk 0 adj + B into regs
    i32x4 a0 = __builtin_nontemporal_load((const i32x4*)(aptr));
    i32x4 a1 = __builtin_nontemporal_load((const i32x4*)(aptr + 4));
    i32x4 a2 = __builtin_nontemporal_load((const i32x4*)(aptr + 8));
    i32x4 a3 = __builtin_nontemporal_load((const i32x4*)(aptr + 12));
    short8 bc0 = *(const short8*)&whb[t * 16];
    short8 bc1 = *(const short8*)&whb[t * 16 + 8];

    __syncthreads();   // s2s ready

    const int arow = w * 16 + c15;

    #pragma unroll 1
    for (int c = 0; c < 8; ++c) {
        const int buf = c & 1;
        const int cn = (c + 1) & 7;

        // prefetch next chunk (wraps harmlessly at c=7)
        i32x4 n0 = __builtin_nontemporal_load((const i32x4*)(aptr + cn * 64));
        i32x4 n1 = __builtin_nontemporal_load((const i32x4*)(aptr + cn * 64 + 4));
        i32x4 n2 = __builtin_nontemporal_load((const i32x4*)(aptr + cn * 64 + 8));
        i32x4 n3 = __builtin_nontemporal_load((const i32x4*)(aptr + cn * 64 + 12));
        short8 bn0 = *(const short8*)&whb[(size_t)cn * 8192 + t * 16];
        short8 bn1 = *(const short8*)&whb[(size_t)cn * 8192 + t * 16 + 8];

        // P compute: 16 j per thread (j = c*64 + q4*16 + 0..15)
        const int sb = c * 64 + q4 * 16;
        uint2 pk0 = pquad(a0, *(const f32x4*)&s2s[sb],      s1v, ssum);
        uint2 pk1 = pquad(a1, *(const f32x4*)&s2s[sb + 4],  s1v, ssum);
        uint2 pk2 = pquad(a2, *(const f32x4*)&s2s[sb + 8],  s1v, ssum);
        uint2 pk3 = pquad(a3, *(const f32x4*)&s2s[sb + 12], s1v, ssum);

        u32x4 w0 = {pk0.x, pk0.y, pk1.x, pk1.y};
        u32x4 w1 = {pk2.x, pk2.y, pk3.x, pk3.y};
        const int sl0 = (q4 * 2)     ^ (r & 7);
        const int sl1 = (q4 * 2 + 1) ^ (r & 7);
        *(u32x4*)&Plds[buf][r * 128 + sl0 * 16] = w0;
        *(u32x4*)&Plds[buf][r * 128 + sl1 * 16] = w1;

        // B to LDS
        *(short8*)&Bl[buf][t * 16] = bc0;
        *(short8*)&Bl[buf][t * 16 + 8] = bc1;

        BAR_LGKM();   // LDS visible; global prefetch stays in flight

        #pragma unroll
        for (int kt = 0; kt < 2; ++kt) {
            const int aslot = (4 * kt + g) ^ (arow & 7);
            short8 af = *(const short8*)&Plds[buf][arow * 128 + aslot * 16];
            #pragma unroll
            for (int nt = 0; nt < 8; ++nt) {
                short8 bfr = *(const short8*)&Bl[buf][((kt * 8 + nt) * 64 + lane) * 8];
                acc[nt] = __builtin_amdgcn_mfma_f32_16x16x32_bf16(af, bfr, acc[nt], 0, 0, 0);
            }
        }

        a0 = n0; a1 = n1; a2 = n2; a3 = n3; bc0 = bn0; bc1 = bn1;
    }

    // row-sum partial: reduce over the 4 q4 lanes (xor 1,2 stay in group)
    {
        float v = ssum;
        v += __shfl_xor(v, 1, 64);
        v += __shfl_xor(v, 2, 64);
        if (q4 == 0) spart[(size_t)bx * 128 + r] = v;
    }

    // unnormalized partial store: row = w*16 + g*4 + q, col = nt*16 + c15
    float* pb = part + (size_t)bx * 16384;
    #pragma unroll
    for (int nt = 0; nt < 8; ++nt) {
        const int col = nt * 16 + c15;
        #pragma unroll
        for (int q = 0; q < 4; ++q) {
            const int row = w * 16 + g * 4 + q;
            pb[row * 128 + col] = acc[nt][q];
        }
    }
}

// K3: combine 4 j-quarter partials, divide by summed row-sums, store out.
// Block = (b, 32-row segment): grid 512.
__global__ __launch_bounds__(256) void gat_combine(
    const float* __restrict__ part, const float* __restrict__ spart,
    float* __restrict__ out)
{
    const int t = threadIdx.x;
    const int bc = blockIdx.x;
    const int b   = bc & 7;
    const int seg = bc >> 3;          // 0..63: rows seg*32 .. +31
    const int it  = seg >> 2;         // i-tile of the main kernel
    const int r0  = (seg & 3) * 32;   // row offset within the tile

    const int cq = t & 31;            // col quad: cols cq*4..+3
    const int rg = t >> 5;            // 8 row groups x 4 rows

    size_t pb[4];
    const float* sp[4];
    #pragma unroll
    for (int js = 0; js < 4; ++js) {
        const int bxm = b + 8 * (it + 16 * js);
        pb[js] = (size_t)bxm * 16384;
        sp[js] = spart + (size_t)bxm * 128;
    }

    float* ob = out + ((size_t)b * NN + it * 128) * FOUT;

    #pragma unroll
    for (int rr = 0; rr < 4; ++rr) {
        const int row = r0 + rg * 4 + rr;   // row within the 128-row tile
        const float sden = sp[0][row] + sp[1][row] + sp[2][row] + sp[3][row];
        const float inv = 1.0f / sden;
        const size_t off = (size_t)row * 128 + cq * 4;
        f32x4 v0 = *(const f32x4*)&part[pb[0] + off];
        f32x4 v1 = *(const f32x4*)&part[pb[1] + off];
        f32x4 v2 = *(const f32x4*)&part[pb[2] + off];
        f32x4 v3 = *(const f32x4*)&part[pb[3] + off];
        f32x4 s = (v0 + v1) + (v2 + v3);
        s[0] *= inv; s[1] *= inv; s[2] *= inv; s[3] *= inv;
        *(f32x4*)&ob[off] = s;
    }
}

extern "C" void kernel_launch(void* const* d_in, const int* in_sizes, int n_in,
                              void* d_out, int out_size, void* d_ws, size_t ws_size,
                              hipStream_t stream) {
    (void)in_sizes; (void)n_in; (void)out_size; (void)ws_size;
    const float* h   = (const float*)d_in[0];
    const int*   adj = (const int*)d_in[1];
    const float* W   = (const float*)d_in[2];
    const float* a   = (const float*)d_in[3];
    float* out = (float*)d_out;

    unsigned short* whpv = (unsigned short*)d_ws;                            // 4 MB
    float* s1g  = (float*)((char*)d_ws + (4u << 20));                        // 64 KB
    float* s2g  = (float*)((char*)d_ws + (4u << 20) + (64u << 10));          // 64 KB
    float* part = (float*)((char*)d_ws + (8u << 20));                        // 32 MB
    float* spart= (float*)((char*)d_ws + (40u << 20));                       // 256 KB

    gat_prep<<<dim3(256), dim3(256), 0, stream>>>(h, W, a, whpv, s1g, s2g);
    gat_main<<<dim3(512), dim3(512), 0, stream>>>(adj, whpv, s1g, s2g, part, spart);
    gat_combine<<<dim3(512), dim3(256), 0, stream>>>(part, spart, out);
}

// Round 11
// 70.227 us; speedup vs baseline: 1.5582x; 1.4113x over previous
//
#include <hip/hip_runtime.h>

#define NB 8
#define NN 2048
#define FIN 256
#define FOUT 128

typedef __attribute__((ext_vector_type(8))) short short8;
typedef __attribute__((ext_vector_type(4))) float f32x4;

static __device__ __forceinline__ unsigned short f2bf(float f) {
    unsigned int u = __float_as_uint(f);
    u += 0x7fffu + ((u >> 16) & 1u);
    return (unsigned short)(u >> 16);
}

// Raw barrier: LDS writes visible (lgkmcnt(0)); global loads stay in flight.
#define BAR_LGKM()                                            \
    do {                                                      \
        asm volatile("s_waitcnt lgkmcnt(0)" ::: "memory");    \
        __builtin_amdgcn_sched_barrier(0);                    \
        __builtin_amdgcn_s_barrier();                         \
        __builtin_amdgcn_sched_barrier(0);                    \
    } while (0)

// K1: unchanged (verified since R1). Wh = h@W fp32; emits s1/s2 + WhPV bf16 fragments.
// WhPV layout per 64-j chunk: [kt(2)][nt(8)][lane(64)][i(8)],
//   element = Wh[j0 + 32*kt + 8*(lane>>4) + i][16*nt + (lane&15)]   (sigma(g,i)=8g+i)
__global__ __launch_bounds__(256) void gat_prep(
    const float* __restrict__ h, const float* __restrict__ W, const float* __restrict__ a,
    unsigned short* __restrict__ whpv, float* __restrict__ s1g, float* __restrict__ s2g)
{
    __shared__ __align__(16) float hT[64 * FIN];
    __shared__ __align__(16) unsigned short pvs[8192];
    const int t = threadIdx.x;
    const int bx = blockIdx.x;
    const int b = bx >> 5;
    const int jt = bx & 31;
    const int j0 = jt * 64;

    const float* hsrc = h + ((size_t)b * NN + j0) * FIN;
    #pragma unroll
    for (int p = 0; p < 16; ++p) {
        int idx = p * 256 + t;
        *(f32x4*)&hT[idx * 4] = *(const f32x4*)&hsrc[idx * 4];
    }
    __syncthreads();

    const int cg = t & 31;
    const int rg = t >> 5;
    float acc[8][4];
    #pragma unroll
    for (int r = 0; r < 8; ++r)
        #pragma unroll
        for (int q = 0; q < 4; ++q) acc[r][q] = 0.f;

    for (int f = 0; f < FIN; f += 4) {
        f32x4 wv[4];
        #pragma unroll
        for (int q = 0; q < 4; ++q) wv[q] = *(const f32x4*)&W[(f + q) * FOUT + cg * 4];
        #pragma unroll
        for (int r = 0; r < 8; ++r) {
            f32x4 hv = *(const f32x4*)&hT[(rg * 8 + r) * FIN + f];
            #pragma unroll
            for (int q = 0; q < 4; ++q) {
                acc[r][0] += hv[q] * wv[q][0];
                acc[r][1] += hv[q] * wv[q][1];
                acc[r][2] += hv[q] * wv[q][2];
                acc[r][3] += hv[q] * wv[q][3];
            }
        }
    }

    f32x4 a1v = *(const f32x4*)&a[cg * 4];
    f32x4 a2v = *(const f32x4*)&a[FOUT + cg * 4];
    #pragma unroll
    for (int r = 0; r < 8; ++r) {
        float p1 = acc[r][0]*a1v[0] + acc[r][1]*a1v[1] + acc[r][2]*a1v[2] + acc[r][3]*a1v[3];
        float p2 = acc[r][0]*a2v[0] + acc[r][1]*a2v[1] + acc[r][2]*a2v[2] + acc[r][3]*a2v[3];
        #pragma unroll
        for (int m = 16; m >= 1; m >>= 1) {
            p1 += __shfl_xor(p1, m, 64);
            p2 += __shfl_xor(p2, m, 64);
        }
        if (cg == 0) {
            s1g[b * NN + j0 + rg * 8 + r] = p1;
            s2g[b * NN + j0 + rg * 8 + r] = p2;
        }
    }

    #pragma unroll
    for (int r = 0; r < 8; ++r) {
        int jl = rg * 8 + r;
        int kt = jl >> 5, j5 = jl & 31, g = j5 >> 3, i = j5 & 7;
        #pragma unroll
        for (int q = 0; q < 4; ++q) {
            int c = cg * 4 + q;
            int lane = g * 16 + (c & 15);
            int nt = c >> 4;
            pvs[((kt * 8 + nt) * 64 + lane) * 8 + i] = f2bf(acc[r][q]);
        }
    }
    __syncthreads();
    unsigned short* dst = whpv + (size_t)(b * 32 + jt) * 8192;
    #pragma unroll
    for (int p = 0; p < 4; ++p) {
        int idx = p * 2048 + t * 8;
        *(short8*)&dst[idx] = *(const short8*)&pvs[idx];
    }
}

// K2 v10: R4's proven inner loop, but grid 1024 (M=32, j-split 2) so 3 blocks/CU are
// RESIDENT (R4's grid=512 capped concurrency at 2). Emits unnormalized partials.
__global__ __launch_bounds__(512, 6) void gat_main(
    const int* __restrict__ adj, const unsigned short* __restrict__ whpv,
    const float* __restrict__ s1g, const float* __restrict__ s2g,
    float* __restrict__ part, float* __restrict__ spart)
{
    __shared__ __align__(16) char Plds[2][32 * 128];       // 2 x 4 KB [row][slot^ (16B)]
    __shared__ __align__(16) unsigned short BL[2][8192];   // 2 x 16 KB B fragments
    __shared__ __align__(16) float s2s[1024];              // 4 KB: own j-half of s2

    const int t = threadIdx.x;
    const int bx = blockIdx.x;
    const int b    = bx & 7;          // XCD affinity: whpv[b] L2-resident
    const int rest = bx >> 3;
    const int it   = rest & 63;       // i-tile (32 rows)
    const int js   = rest >> 6;       // j-half (1024 j = 16 chunks)
    const int i0 = it * 32;
    const int pidx = (b * 64 + it) * 2 + js;

    const int r  = t >> 4;
    const int jq = t & 15;

    const int lane = t & 63;
    const int w = t >> 6;
    const int mt = w & 1;
    const int nb = w >> 1;
    const int arow = mt * 16 + (lane & 15);
    const int g = lane >> 4;

    // stage own half of s2
    const float* s2h = s2g + b * NN + js * 1024;
    float2 s2tmp = *(const float2*)&s2h[t * 2];

    const float s1v = s1g[b * NN + i0 + r];

    f32x4 acc[2];
    acc[0] = (f32x4){0.f, 0.f, 0.f, 0.f};
    acc[1] = (f32x4){0.f, 0.f, 0.f, 0.f};
    float ssum = 0.f;

    const int* aptr = adj + (size_t)b * NN * NN + (size_t)(i0 + r) * NN + js * 1024 + jq * 4;
    const unsigned short* whb = whpv + (size_t)b * 32 * 8192 + (size_t)js * 16 * 8192;

    // depth-2 prefetch registers
    int4   ac[2];
    short8 wf0[2], wf1[2];
    ac[0]  = *(const int4*)aptr;
    wf0[0] = *(const short8*)&whb[t * 8];
    wf1[0] = *(const short8*)&whb[4096 + t * 8];
    ac[1]  = *(const int4*)(aptr + 64);
    wf0[1] = *(const short8*)&whb[8192 + t * 8];
    wf1[1] = *(const short8*)&whb[8192 + 4096 + t * 8];

    *(float2*)&s2s[t * 2] = s2tmp;

    const int pbyte = r * 128 + ((jq >> 1) ^ (r & 7)) * 16 + (jq & 1) * 8;
    const int abyte = arow * 128;

    BAR_LGKM();   // s2s visible; prefetch in flight

    #pragma unroll 2   // keeps slot/buf literal
    for (int jc = 0; jc < 16; ++jc) {
        const int slot = jc & 1;
        const int buf  = jc & 1;

        int4   a_  = ac[slot];
        short8 wc0 = wf0[slot];
        short8 wc1 = wf1[slot];
        f32x4  s2v = *(const f32x4*)&s2s[jc * 64 + jq * 4];

        const int jn = (jc + 2) & 15;   // wraps harmlessly
        ac[slot]  = *(const int4*)(aptr + jn * 64);
        wf0[slot] = *(const short8*)&whb[(size_t)jn * 8192 + t * 8];
        wf1[slot] = *(const short8*)&whb[(size_t)jn * 8192 + 4096 + t * 8];

        float p0, p1, p2, p3;
        {
            float e0 = s1v + s2v[0]; e0 = fmaxf(e0, 0.2f * e0);
            p0 = (a_.x > 0) ? __expf(e0) : 0.f;
            float e1 = s1v + s2v[1]; e1 = fmaxf(e1, 0.2f * e1);
            p1 = (a_.y > 0) ? __expf(e1) : 0.f;
            float e2 = s1v + s2v[2]; e2 = fmaxf(e2, 0.2f * e2);
            p2 = (a_.z > 0) ? __expf(e2) : 0.f;
            float e3 = s1v + s2v[3]; e3 = fmaxf(e3, 0.2f * e3);
            p3 = (a_.w > 0) ? __expf(e3) : 0.f;
        }
        ssum += (p0 + p1) + (p2 + p3);
        unsigned int pk0 = (unsigned int)f2bf(p0) | ((unsigned int)f2bf(p1) << 16);
        unsigned int pk1 = (unsigned int)f2bf(p2) | ((unsigned int)f2bf(p3) << 16);
        uint2 pk = {pk0, pk1};
        *(uint2*)&Plds[buf][pbyte] = pk;

        *(short8*)&BL[buf][t * 8] = wc0;
        *(short8*)&BL[buf][4096 + t * 8] = wc1;

        BAR_LGKM();   // LDS visible; global prefetch stays in flight

        #pragma unroll
        for (int kt = 0; kt < 2; ++kt) {
            int aslot = (4 * kt + g) ^ (arow & 7);
            short8 af = *(const short8*)&Plds[buf][abyte + aslot * 16];
            #pragma unroll
            for (int n = 0; n < 2; ++n) {
                int nt = nb * 2 + n;
                short8 bfr = *(const short8*)&BL[buf][((kt * 8 + nt) * 64 + lane) * 8];
                acc[n] = __builtin_amdgcn_mfma_f32_16x16x32_bf16(af, bfr, acc[n], 0, 0, 0);
            }
        }
    }

    // row-sum partial: reduce over the 16 jq lanes
    {
        float v = ssum;
        #pragma unroll
        for (int m = 8; m >= 1; m >>= 1) v += __shfl_xor(v, m, 64);
        if (jq == 0) spart[(size_t)pidx * 32 + r] = v;
    }

    // unnormalized partial: row = mt*16 + g*4 + q, col = (2nb+n)*16 + c15
    float* pb = part + (size_t)pidx * 4096;
    #pragma unroll
    for (int n = 0; n < 2; ++n) {
        int col = (nb * 2 + n) * 16 + (lane & 15);
        #pragma unroll
        for (int q = 0; q < 4; ++q) {
            int row = mt * 16 + (lane >> 4) * 4 + q;
            pb[row * 128 + col] = acc[n][q];
        }
    }
}

// K3: out = (p0 + p1) / (s0 + s1). Block = (b, it): 512 blocks x 256 thr.
__global__ __launch_bounds__(256) void gat_combine(
    const float* __restrict__ part, const float* __restrict__ spart,
    float* __restrict__ out)
{
    const int t = threadIdx.x;
    const int bc = blockIdx.x;
    const int b  = bc & 7;
    const int it = bc >> 3;
    const int p0i = (b * 64 + it) * 2;

    const float* pa = part + (size_t)p0i * 4096;
    const float* pb = pa + 4096;
    const float* sa = spart + (size_t)p0i * 32;
    const float* sb = sa + 32;

    const int row = t >> 3;          // 0..31
    const int c16 = (t & 7) * 16;    // col base

    const float inv = 1.0f / (sa[row] + sb[row]);
    float* ob = out + ((size_t)b * NN + it * 32 + row) * FOUT + c16;
    const size_t off = (size_t)row * 128 + c16;

    #pragma unroll
    for (int q = 0; q < 4; ++q) {
        f32x4 v0 = *(const f32x4*)&pa[off + q * 4];
        f32x4 v1 = *(const f32x4*)&pb[off + q * 4];
        f32x4 s = v0 + v1;
        s[0] *= inv; s[1] *= inv; s[2] *= inv; s[3] *= inv;
        *(f32x4*)&ob[q * 4] = s;
    }
}

extern "C" void kernel_launch(void* const* d_in, const int* in_sizes, int n_in,
                              void* d_out, int out_size, void* d_ws, size_t ws_size,
                              hipStream_t stream) {
    (void)in_sizes; (void)n_in; (void)out_size; (void)ws_size;
    const float* h   = (const float*)d_in[0];
    const int*   adj = (const int*)d_in[1];
    const float* W   = (const float*)d_in[2];
    const float* a   = (const float*)d_in[3];
    float* out = (float*)d_out;

    unsigned short* whpv = (unsigned short*)d_ws;                            // 4 MB
    float* s1g  = (float*)((char*)d_ws + (4u << 20));                        // 64 KB
    float* s2g  = (float*)((char*)d_ws + (4u << 20) + (64u << 10));          // 64 KB
    float* part = (float*)((char*)d_ws + (8u << 20));                        // 16 MB
    float* spart= (float*)((char*)d_ws + (24u << 20));                       // 128 KB

    gat_prep<<<dim3(256), dim3(256), 0, stream>>>(h, W, a, whpv, s1g, s2g);
    gat_main<<<dim3(1024), dim3(512), 0, stream>>>(adj, whpv, s1g, s2g, part, spart);
    gat_combine<<<dim3(512), dim3(256), 0, stream>>>(part, spart, out);
}

// Round 12
// 64.755 us; speedup vs baseline: 1.6898x; 1.0845x over previous
//
#include <hip/hip_runtime.h>

#define NB 8
#define NN 2048
#define FIN 256
#define FOUT 128

typedef __attribute__((ext_vector_type(8))) short short8;
typedef __attribute__((ext_vector_type(4))) float f32x4;

static __device__ __forceinline__ unsigned short f2bf(float f) {
    unsigned int u = __float_as_uint(f);
    u += 0x7fffu + ((u >> 16) & 1u);
    return (unsigned short)(u >> 16);
}

// T12 recipe (learn_hip m214/m240): pack 2 f32 -> 2 bf16 in one instruction. lo = %1.
static __device__ __forceinline__ unsigned int cvtpk(float lo, float hi) {
    unsigned int d;
    asm("v_cvt_pk_bf16_f32 %0, %1, %2" : "=v"(d) : "v"(lo), "v"(hi));
    return d;
}

// Raw barrier: LDS writes visible (lgkmcnt(0)); global loads stay in flight.
#define BAR_LGKM()                                            \
    do {                                                      \
        asm volatile("s_waitcnt lgkmcnt(0)" ::: "memory");    \
        __builtin_amdgcn_sched_barrier(0);                    \
        __builtin_amdgcn_s_barrier();                         \
        __builtin_amdgcn_sched_barrier(0);                    \
    } while (0)

// K1: unchanged (verified since R1). Wh = h@W fp32; emits s1/s2 + WhPV bf16 fragments.
// WhPV layout per 64-j chunk: [kt(2)][nt(8)][lane(64)][i(8)],
//   element = Wh[j0 + 32*kt + 8*(lane>>4) + i][16*nt + (lane&15)]   (sigma(g,i)=8g+i)
__global__ __launch_bounds__(256) void gat_prep(
    const float* __restrict__ h, const float* __restrict__ W, const float* __restrict__ a,
    unsigned short* __restrict__ whpv, float* __restrict__ s1g, float* __restrict__ s2g)
{
    __shared__ __align__(16) float hT[64 * FIN];
    __shared__ __align__(16) unsigned short pvs[8192];
    const int t = threadIdx.x;
    const int bx = blockIdx.x;
    const int b = bx >> 5;
    const int jt = bx & 31;
    const int j0 = jt * 64;

    const float* hsrc = h + ((size_t)b * NN + j0) * FIN;
    #pragma unroll
    for (int p = 0; p < 16; ++p) {
        int idx = p * 256 + t;
        *(f32x4*)&hT[idx * 4] = *(const f32x4*)&hsrc[idx * 4];
    }
    __syncthreads();

    const int cg = t & 31;
    const int rg = t >> 5;
    float acc[8][4];
    #pragma unroll
    for (int r = 0; r < 8; ++r)
        #pragma unroll
        for (int q = 0; q < 4; ++q) acc[r][q] = 0.f;

    for (int f = 0; f < FIN; f += 4) {
        f32x4 wv[4];
        #pragma unroll
        for (int q = 0; q < 4; ++q) wv[q] = *(const f32x4*)&W[(f + q) * FOUT + cg * 4];
        #pragma unroll
        for (int r = 0; r < 8; ++r) {
            f32x4 hv = *(const f32x4*)&hT[(rg * 8 + r) * FIN + f];
            #pragma unroll
            for (int q = 0; q < 4; ++q) {
                acc[r][0] += hv[q] * wv[q][0];
                acc[r][1] += hv[q] * wv[q][1];
                acc[r][2] += hv[q] * wv[q][2];
                acc[r][3] += hv[q] * wv[q][3];
            }
        }
    }

    f32x4 a1v = *(const f32x4*)&a[cg * 4];
    f32x4 a2v = *(const f32x4*)&a[FOUT + cg * 4];
    #pragma unroll
    for (int r = 0; r < 8; ++r) {
        float p1 = acc[r][0]*a1v[0] + acc[r][1]*a1v[1] + acc[r][2]*a1v[2] + acc[r][3]*a1v[3];
        float p2 = acc[r][0]*a2v[0] + acc[r][1]*a2v[1] + acc[r][2]*a2v[2] + acc[r][3]*a2v[3];
        #pragma unroll
        for (int m = 16; m >= 1; m >>= 1) {
            p1 += __shfl_xor(p1, m, 64);
            p2 += __shfl_xor(p2, m, 64);
        }
        if (cg == 0) {
            s1g[b * NN + j0 + rg * 8 + r] = p1;
            s2g[b * NN + j0 + rg * 8 + r] = p2;
        }
    }

    #pragma unroll
    for (int r = 0; r < 8; ++r) {
        int jl = rg * 8 + r;
        int kt = jl >> 5, j5 = jl & 31, g = j5 >> 3, i = j5 & 7;
        #pragma unroll
        for (int q = 0; q < 4; ++q) {
            int c = cg * 4 + q;
            int lane = g * 16 + (c & 15);
            int nt = c >> 4;
            pvs[((kt * 8 + nt) * 64 + lane) * 8 + i] = f2bf(acc[r][q]);
        }
    }
    __syncthreads();
    unsigned short* dst = whpv + (size_t)(b * 32 + jt) * 8192;
    #pragma unroll
    for (int p = 0; p < 4; ++p) {
        int idx = p * 2048 + t * 8;
        *(short8*)&dst[idx] = *(const short8*)&pvs[idx];
    }
}

// K2 v11: R4's verified math/mapping, 4 chunks (256 j) per barrier pair.
// Per super-iter: P-phase {consume depth-4 reg ring, write 4 P-tiles + 4 B-chunks
// to LDS, prefetch next 4 chunks} -> BAR -> 16 MFMA/wave -> BAR. Barriers/block:
// 64 -> 16. LDS exactly 80 KB -> 2 blocks/CU.
__global__ __launch_bounds__(512, 4) void gat_main(
    const int* __restrict__ adj, const unsigned short* __restrict__ whpv,
    const float* __restrict__ s1g, const float* __restrict__ s2g, float* __restrict__ out)
{
    __shared__ __align__(16) char pool[81920];
    unsigned short* BL = (unsigned short*)pool;      // 4 chunks x 8192 shorts (64 KB)
    char* Plds = pool + 65536;                       // 4 chunks x 4096 B (16 KB)

    const int t = threadIdx.x;
    const int bx = blockIdx.x;
    const int b  = bx & 7;            // XCD affinity: whpv[b] L2-resident
    const int i0 = (bx >> 3) * 32;

    const int r  = t >> 4;            // P row 0..31
    const int jq = t & 15;            // j-quad

    const int lane = t & 63;
    const int w = t >> 6;
    const int mt = w & 1;
    const int nb = w >> 1;
    const int arow = mt * 16 + (lane & 15);
    const int g = lane >> 4;

    const float s1v = s1g[b * NN + i0 + r];

    f32x4 acc[2];
    acc[0] = (f32x4){0.f, 0.f, 0.f, 0.f};
    acc[1] = (f32x4){0.f, 0.f, 0.f, 0.f};
    float ssum = 0.f;

    const int* aptr = adj + (size_t)b * NN * NN + (size_t)(i0 + r) * NN + jq * 4;
    const unsigned short* whb = whpv + (size_t)b * 32 * 8192;
    const float* s2b = s2g + b * NN;

    // depth-4 register ring (literal-indexed via macros)
    int4   ac0, ac1, ac2, ac3;
    short8 wa0, wa1, wa2, wa3, wb0, wb1, wb2, wb3;
    f32x4  s20, s21, s22, s23;

#define PRELOAD(C)                                                          \
    ac##C = *(const int4*)(aptr + (C) * 64);                                \
    wa##C = *(const short8*)&whb[(size_t)(C) * 8192 + t * 8];               \
    wb##C = *(const short8*)&whb[(size_t)(C) * 8192 + 4096 + t * 8];        \
    s2##C = *(const f32x4*)&s2b[(C) * 64 + jq * 4];

    PRELOAD(0) PRELOAD(1) PRELOAD(2) PRELOAD(3)
#undef PRELOAD

    const int pbyte = r * 128 + ((jq >> 1) ^ (r & 7)) * 16 + (jq & 1) * 8;
    const int abyte = arow * 128;

#define PPHASE(C, S)                                                        \
    do {                                                                    \
        int4   a_  = ac##C;                                                 \
        short8 w0_ = wa##C;                                                 \
        short8 w1_ = wb##C;                                                 \
        f32x4  s2v = s2##C;                                                 \
        const int jn = ((S) * 4 + 4 + (C)) & 31;                            \
        ac##C = *(const int4*)(aptr + jn * 64);                             \
        wa##C = *(const short8*)&whb[(size_t)jn * 8192 + t * 8];            \
        wb##C = *(const short8*)&whb[(size_t)jn * 8192 + 4096 + t * 8];     \
        s2##C = *(const f32x4*)&s2b[jn * 64 + jq * 4];                      \
        float e0 = s1v + s2v[0]; e0 = fmaxf(e0, 0.2f * e0);                 \
        float p0 = (a_.x > 0) ? __expf(e0) : 0.f;                           \
        float e1 = s1v + s2v[1]; e1 = fmaxf(e1, 0.2f * e1);                 \
        float p1 = (a_.y > 0) ? __expf(e1) : 0.f;                           \
        float e2 = s1v + s2v[2]; e2 = fmaxf(e2, 0.2f * e2);                 \
        float p2 = (a_.z > 0) ? __expf(e2) : 0.f;                           \
        float e3 = s1v + s2v[3]; e3 = fmaxf(e3, 0.2f * e3);                 \
        float p3 = (a_.w > 0) ? __expf(e3) : 0.f;                           \
        ssum += (p0 + p1) + (p2 + p3);                                      \
        uint2 pk = {cvtpk(p0, p1), cvtpk(p2, p3)};                          \
        *(uint2*)&Plds[(C) * 4096 + pbyte] = pk;                            \
        *(short8*)&BL[(C) * 8192 + t * 8] = w0_;                            \
        *(short8*)&BL[(C) * 8192 + 4096 + t * 8] = w1_;                     \
    } while (0)

#define MPHASE(C)                                                           \
    do {                                                                    \
        _Pragma("unroll")                                                   \
        for (int kt = 0; kt < 2; ++kt) {                                    \
            const int aslot = (4 * kt + g) ^ (arow & 7);                    \
            short8 af = *(const short8*)&Plds[(C) * 4096 + abyte + aslot * 16]; \
            _Pragma("unroll")                                               \
            for (int n = 0; n < 2; ++n) {                                   \
                const int nt = nb * 2 + n;                                  \
                short8 bfr = *(const short8*)&BL[(C) * 8192 + ((kt * 8 + nt) * 64 + lane) * 8]; \
                acc[n] = __builtin_amdgcn_mfma_f32_16x16x32_bf16(af, bfr, acc[n], 0, 0, 0); \
            }                                                               \
        }                                                                   \
    } while (0)

    #pragma unroll 1
    for (int s = 0; s < 8; ++s) {
        PPHASE(0, s); PPHASE(1, s); PPHASE(2, s); PPHASE(3, s);
        BAR_LGKM();   // P/B tiles visible; 16 prefetch loads stay in flight
        MPHASE(0); MPHASE(1); MPHASE(2); MPHASE(3);
        BAR_LGKM();   // MFMA reads done before next P-phase overwrites
    }
#undef PPHASE
#undef MPHASE

    // row-sum: reduce ssum over the 16 jq lanes; stash in (now dead) LDS
    float* Sden = (float*)pool;
    {
        float v = ssum;
        #pragma unroll
        for (int m = 8; m >= 1; m >>= 1) v += __shfl_xor(v, m, 64);
        if (jq == 0) Sden[r] = v;
    }
    __syncthreads();

    // epilogue: D layout col = lane&15, row = (lane>>4)*4 + q
    float* ob = out + ((size_t)b * NN + i0) * FOUT;
    #pragma unroll
    for (int n = 0; n < 2; ++n) {
        int col = (nb * 2 + n) * 16 + (lane & 15);
        #pragma unroll
        for (int q = 0; q < 4; ++q) {
            int row = mt * 16 + (lane >> 4) * 4 + q;
            ob[(size_t)row * FOUT + col] = acc[n][q] / Sden[row];
        }
    }
}

extern "C" void kernel_launch(void* const* d_in, const int* in_sizes, int n_in,
                              void* d_out, int out_size, void* d_ws, size_t ws_size,
                              hipStream_t stream) {
    (void)in_sizes; (void)n_in; (void)out_size; (void)ws_size;
    const float* h   = (const float*)d_in[0];
    const int*   adj = (const int*)d_in[1];
    const float* W   = (const float*)d_in[2];
    const float* a   = (const float*)d_in[3];
    float* out = (float*)d_out;

    unsigned short* whpv = (unsigned short*)d_ws;                            // 4 MB
    float* s1g = (float*)((char*)d_ws + (4u << 20));                         // 64 KB
    float* s2g = (float*)((char*)d_ws + (4u << 20) + (64u << 10));           // 64 KB

    gat_prep<<<dim3(256), dim3(256), 0, stream>>>(h, W, a, whpv, s1g, s2g);
    gat_main<<<dim3(512), dim3(512), 0, stream>>>(adj, whpv, s1g, s2g, out);
}